// Round 3
// baseline (2450.644 us; speedup 1.0000x reference)
//
#include <hip/hip_runtime.h>

constexpr int S   = 4096;
constexpr int D   = 64;
constexpr int NK  = 12;     // log2(4096) gathered positions
constexpr int TPB = 256;    // rows per block == threads per block
constexpr int BH  = 32;     // B*H
constexpr long long CTX_ELEMS = (long long)BH * S * D;   // 8388608 floats

// inds[k] = 4096 - 2^(12-k) = S - (S >> k), k = 0..11
//         = [0, 2048, 3072, 3584, 3840, 3968, 4032, 4064, 4080, 4088, 4092, 4094]
__device__ __forceinline__ int log_ind(int k) { return S - (S >> k); }

__global__ __launch_bounds__(TPB, 2)
void logtrans_kernel(const float* __restrict__ Qg,
                     const float* __restrict__ Kg,
                     const float* __restrict__ Vg,
                     const int*   __restrict__ maskg,
                     float*       __restrict__ out_ctx,
                     float*       __restrict__ out_attn)
{
    __shared__ float kls[NK * D];
    __shared__ float vls[NK * D];

    const int t    = threadIdx.x;
    const int row0 = blockIdx.x * TPB;          // 256 | 4096 -> one (b,h) per block
    const int bh   = row0 >> 12;                // row0 / S
    const long long kvbase = (long long)bh * (S * D);

    // stage the 12 gathered K/V rows into LDS (768 floats each)
    for (int e = t; e < NK * D; e += TPB) {
        const int k = e >> 6;
        const int d = e & 63;
        const long long off = kvbase + (long long)log_ind(k) * D + d;
        kls[e] = Kg[off];
        vls[e] = Vg[off];
    }
    __syncthreads();

    const int r = row0 + t;

    // this thread's Q row: 64 fp32 via 16 x 16B loads
    float q[D];
    const float4* q16 = (const float4*)(Qg + (long long)r * D);
    #pragma unroll
    for (int i = 0; i < D / 4; ++i) {
        float4 u = q16[i];
        q[4*i+0] = u.x; q[4*i+1] = u.y; q[4*i+2] = u.z; q[4*i+3] = u.w;
    }

    // scores = Q . K_g / sqrt(64)
    float sc[NK];
    #pragma unroll
    for (int k = 0; k < NK; ++k) {
        const float4* kp = (const float4*)(kls + k * D);
        float dot = 0.f;
        #pragma unroll
        for (int i = 0; i < D / 4; ++i) {
            float4 kv = kp[i];
            dot += q[4*i+0] * kv.x;
            dot += q[4*i+1] * kv.y;
            dot += q[4*i+2] * kv.z;
            dot += q[4*i+3] * kv.w;
        }
        sc[k] = dot * 0.125f;
    }

    // mask gather: mask[b,h,q,inds[k]]  (mask TRUE -> -1e9)
    const long long mbase = (long long)r * S;
    #pragma unroll
    for (int k = 0; k < NK; ++k) {
        if (maskg[mbase + log_ind(k)] != 0) sc[k] = -1.0e9f;
    }

    // softmax over 12
    float m = sc[0];
    #pragma unroll
    for (int k = 1; k < NK; ++k) m = fmaxf(m, sc[k]);
    float a[NK];
    float sum = 0.f;
    #pragma unroll
    for (int k = 0; k < NK; ++k) { a[k] = __expf(sc[k] - m); sum += a[k]; }
    const float inv = 1.0f / sum;
    #pragma unroll
    for (int k = 0; k < NK; ++k) a[k] *= inv;

    // write attn: 12 floats/row, 48B/row -> 16B aligned -> 3 float4 stores
    float4* oa = (float4*)(out_attn + (long long)r * NK);
    #pragma unroll
    for (int k = 0; k < 3; ++k) {
        float4 p;
        p.x = a[4*k+0]; p.y = a[4*k+1]; p.z = a[4*k+2]; p.w = a[4*k+3];
        oa[k] = p;
    }

    // context = attn . V_g -> 16 float4 stores
    float4* oc = (float4*)(out_ctx + (long long)r * D);
    #pragma unroll
    for (int i = 0; i < D / 4; ++i) {
        float ax = 0.f, ay = 0.f, az = 0.f, aw = 0.f;
        #pragma unroll
        for (int k = 0; k < NK; ++k) {
            float4 vv = ((const float4*)(vls + k * D))[i];
            ax += a[k] * vv.x;
            ay += a[k] * vv.y;
            az += a[k] * vv.z;
            aw += a[k] * vv.w;
        }
        float4 p; p.x = ax; p.y = ay; p.z = az; p.w = aw;
        oc[i] = p;
    }
}

extern "C" void kernel_launch(void* const* d_in, const int* in_sizes, int n_in,
                              void* d_out, int out_size, void* d_ws, size_t ws_size,
                              hipStream_t stream) {
    const float* Q    = (const float*)d_in[0];
    const float* K    = (const float*)d_in[1];
    const float* V    = (const float*)d_in[2];
    const int*   mask = (const int*)d_in[3];
    float* out_ctx  = (float*)d_out;
    float* out_attn = out_ctx + CTX_ELEMS;

    const int total_rows = BH * S;              // 131072
    logtrans_kernel<<<dim3(total_rows / TPB), dim3(TPB), 0, stream>>>(
        Q, K, V, mask, out_ctx, out_attn);
}

// Round 4
// 2338.331 us; speedup vs baseline: 1.0480x; 1.0480x over previous
//
#include <hip/hip_runtime.h>

constexpr int S   = 4096;
constexpr int D   = 64;
constexpr int NK  = 12;     // log2(4096) gathered positions
constexpr int TPB = 256;    // rows per block == threads per block
constexpr int BH  = 32;     // B*H
constexpr int QSTRIDE = D + 1;   // 65: LDS row pad -> bank (t+d)%32, 2-way = free
constexpr long long CTX_ELEMS = (long long)BH * S * D;   // 8388608 floats

// inds[k] = 4096 - 2^(12-k) = S - (S >> k), k = 0..11
//         = [0, 2048, 3072, 3584, 3840, 3968, 4032, 4064, 4080, 4088, 4092, 4094]
__device__ __forceinline__ int log_ind(int k) { return S - (S >> k); }

__global__ __launch_bounds__(TPB, 2)
void logtrans_kernel(const float* __restrict__ Qg,
                     const float* __restrict__ Kg,
                     const float* __restrict__ Vg,
                     const int*   __restrict__ maskg,
                     float*       __restrict__ out_ctx,
                     float*       __restrict__ out_attn)
{
    __shared__ float kls[NK * D];            // 3 KB
    __shared__ float vls[NK * D];            // 3 KB
    __shared__ float qs[TPB * QSTRIDE];      // 65 KB; Q rows, later reused for ctx

    const int t    = threadIdx.x;
    const int row0 = blockIdx.x * TPB;       // 256 | 4096 -> one (b,h) per block
    const int bh   = row0 >> 12;
    const long long kvbase = (long long)bh * (S * D);

    // ---- stage K/V gathered rows, float4-coalesced (2*12*16 = 384 float4s)
    for (int e = t; e < 2 * NK * (D / 4); e += TPB) {
        const int m  = e >= NK * (D / 4);    // 0 = K, 1 = V
        const int i  = m ? e - NK * (D / 4) : e;
        const int k  = i >> 4;
        const int d4 = (i & 15) * 4;
        const float* src = (m ? Vg : Kg) + kvbase + (long long)log_ind(k) * D + d4;
        float4 v = *(const float4*)src;
        float* dst = (m ? vls : kls) + k * D + d4;
        dst[0] = v.x; dst[1] = v.y; dst[2] = v.z; dst[3] = v.w;
    }

    // ---- stage this block's 256 Q rows (64 KB) with fully-coalesced float4 loads
    const float4* qsrc = (const float4*)(Qg + (long long)row0 * D);  // 4096 float4
    #pragma unroll
    for (int j = 0; j < 16; ++j) {
        const int e  = j * TPB + t;          // consecutive lanes -> consecutive 16B
        float4 v = qsrc[e];
        float* dst = qs + (e >> 4) * QSTRIDE + (e & 15) * 4;
        dst[0] = v.x; dst[1] = v.y; dst[2] = v.z; dst[3] = v.w;
    }

    // ---- mask gather (independent of LDS: issue before the barrier, overlap it)
    // 10 scalar loads + one int4 covering {4092, 4094}
    const long long mbase = (long long)(row0 + t) * S;
    int mk[NK];
    #pragma unroll
    for (int k = 0; k < 10; ++k) mk[k] = maskg[mbase + log_ind(k)];
    {
        int4 tail = *(const int4*)(maskg + mbase + 4092);  // 16B-aligned
        mk[10] = tail.x;                     // idx 4092
        mk[11] = tail.z;                     // idx 4094
    }

    __syncthreads();

    // ---- Q row from LDS (b32 reads, 2-way bank alias = free)
    float q[D];
    #pragma unroll
    for (int d = 0; d < D; ++d) q[d] = qs[t * QSTRIDE + d];

    // ---- scores = Q.K_g / 8, masked
    float sc[NK];
    #pragma unroll
    for (int k = 0; k < NK; ++k) {
        const float4* kp = (const float4*)(kls + k * D);  // broadcast reads
        float dot = 0.f;
        #pragma unroll
        for (int i = 0; i < D / 4; ++i) {
            float4 kv = kp[i];
            dot += q[4*i+0] * kv.x + q[4*i+1] * kv.y
                 + q[4*i+2] * kv.z + q[4*i+3] * kv.w;
        }
        sc[k] = mk[k] ? -1.0e9f : dot * 0.125f;
    }

    // ---- softmax over 12
    float m = sc[0];
    #pragma unroll
    for (int k = 1; k < NK; ++k) m = fmaxf(m, sc[k]);
    float a[NK];
    float sum = 0.f;
    #pragma unroll
    for (int k = 0; k < NK; ++k) { a[k] = __expf(sc[k] - m); sum += a[k]; }
    const float inv = 1.0f / sum;
    #pragma unroll
    for (int k = 0; k < NK; ++k) a[k] *= inv;

    // ---- attn out: 48B/row, 3 float4 stores (small; direct)
    float4* oa = (float4*)(out_attn + (long long)(row0 + t) * NK);
    #pragma unroll
    for (int k = 0; k < 3; ++k) {
        float4 p;
        p.x = a[4*k+0]; p.y = a[4*k+1]; p.z = a[4*k+2]; p.w = a[4*k+3];
        oa[k] = p;
    }

    // ---- context = attn.V_g into registers
    float c[D];
    #pragma unroll
    for (int i = 0; i < D / 4; ++i) {
        float ax = 0.f, ay = 0.f, az = 0.f, aw = 0.f;
        #pragma unroll
        for (int k = 0; k < NK; ++k) {
            float4 vv = ((const float4*)(vls + k * D))[i];  // broadcast reads
            ax += a[k] * vv.x; ay += a[k] * vv.y;
            az += a[k] * vv.z; aw += a[k] * vv.w;
        }
        c[4*i+0] = ax; c[4*i+1] = ay; c[4*i+2] = az; c[4*i+3] = aw;
    }

    // ---- round-trip ctx through qs for fully-coalesced float4 stores
    __syncthreads();                          // all reads of qs/vls done
    #pragma unroll
    for (int d = 0; d < D; ++d) qs[t * QSTRIDE + d] = c[d];
    __syncthreads();

    float4* cdst = (float4*)(out_ctx + (long long)row0 * D);
    #pragma unroll
    for (int j = 0; j < 16; ++j) {
        const int e = j * TPB + t;            // consecutive lanes -> consecutive 16B
        const float* sp = qs + (e >> 4) * QSTRIDE + (e & 15) * 4;
        float4 v;
        v.x = sp[0]; v.y = sp[1]; v.z = sp[2]; v.w = sp[3];
        cdst[e] = v;
    }
}

extern "C" void kernel_launch(void* const* d_in, const int* in_sizes, int n_in,
                              void* d_out, int out_size, void* d_ws, size_t ws_size,
                              hipStream_t stream) {
    const float* Q    = (const float*)d_in[0];
    const float* K    = (const float*)d_in[1];
    const float* V    = (const float*)d_in[2];
    const int*   mask = (const int*)d_in[3];
    float* out_ctx  = (float*)d_out;
    float* out_attn = out_ctx + CTX_ELEMS;

    const int total_rows = BH * S;            // 131072
    logtrans_kernel<<<dim3(total_rows / TPB), dim3(TPB), 0, stream>>>(
        Q, K, V, mask, out_ctx, out_attn);
}